// Round 12
// baseline (210.065 us; speedup 1.0000x reference)
//
#include <hip/hip_runtime.h>
#include <hip/hip_bf16.h>

typedef __attribute__((ext_vector_type(8))) short short8;
typedef __attribute__((ext_vector_type(4))) float f32x4;
typedef __attribute__((ext_vector_type(4))) short short4v;

// Problem constants
#define BB 8
#define NN 1024
#define DD 512
#define OO 512
#define HH 8
#define HD 64
#define MM (BB * NN)  // 8192

#define QSC 0.18033688f       // 0.125 * log2(e): folded into Q at projection
#define KSHIFT -11.54156032f  // -8*log2(e): softmax shift, fused into key bias
#define KMASKED -30000.0f     // masked key: exp2 underflows to exactly 0

// Async global->LDS, 16B/lane (m97 recipe). LDS dest = wave-uniform base +
// lane*16 -> unpadded tiles.
__device__ __forceinline__ void gload_lds16(const void* g, void* l) {
  __builtin_amdgcn_global_load_lds(
      (const __attribute__((address_space(1))) void*)g,
      (__attribute__((address_space(3))) void*)l, 16, 0, 0);
}

__device__ __forceinline__ uint2 cvt4(float4 v) {
  union { uint2 u; __hip_bfloat16 h[4]; } t;
  t.h[0] = __float2bfloat16(v.x);
  t.h[1] = __float2bfloat16(v.y);
  t.h[2] = __float2bfloat16(v.z);
  t.h[3] = __float2bfloat16(v.w);
  return t.u;
}

// ---------------------------------------------------------------------------
// Input conversion. PROVEN: float inputs fp32, mask int32 {0,1}, output fp32.
// ---------------------------------------------------------------------------
#define SEG_N 10
struct ConvArgs {
  const float* src[SEG_N];
  __hip_bfloat16* dst[SEG_N];
  int n4[SEG_N];
};

__global__ void convert_kernel(ConvArgs a) {
  const int t = blockIdx.y;
  const int n4 = a.n4[t];
  const float4* fs = (const float4*)a.src[t];
  uint2* d = (uint2*)a.dst[t];
  for (int i = blockIdx.x * blockDim.x + threadIdx.x; i < n4;
       i += gridDim.x * blockDim.x)
    d[i] = cvt4(fs[i]);
}

// ---------------------------------------------------------------------------
// 128x128-tile GEMM, BK=64 via two-plane staging: smem = [A0|A1|B0|B1],
// each plane 128x32 (gload_lds linear-dest rule holds per plane). 8 barrier
// rounds, 8 gload_lds + 32 MFMA per round. B = [qkvw ; wr] (2048 rows).
// Grid 1024 = 64 rowparts x 16 colparts, XCD-banded.
// part 0: Q (pre-scaled QSC) -> [B,H,N,64]
// part 1: K                  -> [B,H,N,64]
// part 2: V (LDS transpose)  -> [B,H,64,N]
// part 3: 0.5*(x@wr^T + br)  -> fp32 d_out (residual half, pre-written;
//                               ffn_fused accumulates the h-half onto it)
// ---------------------------------------------------------------------------
__global__ __launch_bounds__(256) void gemm_qkv(
    const __hip_bfloat16* __restrict__ A0, const __hip_bfloat16* __restrict__ B0,
    const __hip_bfloat16* __restrict__ bias0, const __hip_bfloat16* __restrict__ bias1,
    __hip_bfloat16* __restrict__ out0, __hip_bfloat16* __restrict__ out1,
    __hip_bfloat16* __restrict__ out2, float* __restrict__ outf, int Kd) {
  __shared__ __align__(16) __hip_bfloat16 smem[16384];  // 4 planes x 128x32

  const int tid  = threadIdx.x;
  const int wave = tid >> 6;
  const int lane = tid & 63;
  const int fl   = lane & 15;
  const int fk   = (lane >> 4) * 8;
  const int wm   = (wave & 1) * 64;
  const int wn   = (wave >> 1) * 64;
  // XCD-banded swizzle (1024 blocks = 64 rowparts x 16 colparts)
  const int bid     = blockIdx.x;
  const int rowpart = 8 * (bid & 7) + ((bid >> 3) & 7);
  const int colpart = bid >> 6;
  const int m0 = rowpart * 128;
  const int n0 = colpart * 128;
  const int glr  = lane >> 2;
  const int glc  = (lane & 3) * 8;

  f32x4 acc[4][4];
#pragma unroll
  for (int i = 0; i < 4; ++i)
#pragma unroll
    for (int j = 0; j < 4; ++j) acc[i][j] = (f32x4){0.f, 0.f, 0.f, 0.f};

  char* lb = (char*)smem;
  for (int k0 = 0; k0 < Kd; k0 += 64) {
    __syncthreads();
    // A plane 0: cols k0..k0+31, rows m0..m0+127
    gload_lds16(A0 + (size_t)(m0 + wave * 16 + glr) * Kd + k0 + glc,
                lb + wave * 1024 + lane * 16);
    gload_lds16(A0 + (size_t)(m0 + 64 + wave * 16 + glr) * Kd + k0 + glc,
                lb + (wave + 4) * 1024 + lane * 16);
    // A plane 1: cols k0+32..k0+63
    gload_lds16(A0 + (size_t)(m0 + wave * 16 + glr) * Kd + k0 + 32 + glc,
                lb + 8192 + wave * 1024 + lane * 16);
    gload_lds16(A0 + (size_t)(m0 + 64 + wave * 16 + glr) * Kd + k0 + 32 + glc,
                lb + 8192 + (wave + 4) * 1024 + lane * 16);
    // B plane 0
    gload_lds16(B0 + (size_t)(n0 + wave * 16 + glr) * Kd + k0 + glc,
                lb + 16384 + wave * 1024 + lane * 16);
    gload_lds16(B0 + (size_t)(n0 + 64 + wave * 16 + glr) * Kd + k0 + glc,
                lb + 16384 + (wave + 4) * 1024 + lane * 16);
    // B plane 1
    gload_lds16(B0 + (size_t)(n0 + wave * 16 + glr) * Kd + k0 + 32 + glc,
                lb + 24576 + wave * 1024 + lane * 16);
    gload_lds16(B0 + (size_t)(n0 + 64 + wave * 16 + glr) * Kd + k0 + 32 + glc,
                lb + 24576 + (wave + 4) * 1024 + lane * 16);
    __syncthreads();

#pragma unroll
    for (int kh = 0; kh < 2; ++kh) {
      const __hip_bfloat16* Ap = smem + kh * 4096;
      const __hip_bfloat16* Bp = smem + 8192 + kh * 4096;
      short8 af[4], bfr[4];
#pragma unroll
      for (int i = 0; i < 4; ++i)
        af[i] = *(const short8*)&Ap[(wm + i * 16 + fl) * 32 + fk];
#pragma unroll
      for (int j = 0; j < 4; ++j)
        bfr[j] = *(const short8*)&Bp[(wn + j * 16 + fl) * 32 + fk];
#pragma unroll
      for (int i = 0; i < 4; ++i)
#pragma unroll
        for (int j = 0; j < 4; ++j)
          acc[i][j] = __builtin_amdgcn_mfma_f32_16x16x32_bf16(af[i], bfr[j],
                                                              acc[i][j], 0, 0, 0);
    }
  }

  const int rb = (lane >> 4) * 4;
  const int part = n0 >> 9;  // block-uniform: 0=Q 1=K 2=V 3=wr
  if (part < 2) {
    __hip_bfloat16* dst = (part == 0) ? out0 : out1;
    const float scf = (part == 0) ? QSC : 1.0f;
#pragma unroll
    for (int j = 0; j < 4; ++j) {
      const int colb  = n0 + wn + j * 16;
      const int o     = colb & 511;
      const int headq = o >> 6;
      const int d     = (o & 63) + fl;
      const float bi  = __bfloat162float(bias0[colb + fl]);
#pragma unroll
      for (int i = 0; i < 4; ++i) {
#pragma unroll
        for (int r = 0; r < 4; ++r) {
          const int row = m0 + wm + i * 16 + rb + r;
          const int bb  = row >> 10;
          const int nn  = row & 1023;
          dst[((size_t)((bb << 3) + headq) * NN + nn) * HD + d] =
              __float2bfloat16((acc[i][j][r] + bi) * scf);
        }
      }
    }
  } else if (part == 2) {
    // V: transpose 64x16 pieces through LDS, coalesced dwordx4 stores
    __syncthreads();  // uniform; smem free for scratch
    __hip_bfloat16* tsc = smem + wave * 1120;  // 16 x 70 per wave
    const int bb  = (m0 + wm) >> 10;
    const int nnb = (m0 + wm) & 1023;
    const int dl  = lane >> 2;
    const int cc  = (lane & 3) * 16;
#pragma unroll
    for (int j = 0; j < 4; ++j) {
      const int colb  = n0 + wn + j * 16;
      const int o     = colb & 511;
      const int headq = o >> 6;
      const int dbase = o & 63;
      const float bi  = __bfloat162float(bias0[colb + fl]);
#pragma unroll
      for (int i = 0; i < 4; ++i) {
#pragma unroll
        for (int r = 0; r < 4; ++r) {
          const int rr = i * 16 + rb + r;
          tsc[fl * 70 + rr] = __float2bfloat16(acc[i][j][r] + bi);
        }
      }
      uint4 r0 = *(const uint4*)&tsc[dl * 70 + cc];
      uint4 r1 = *(const uint4*)&tsc[dl * 70 + cc + 8];
      __hip_bfloat16* vdst =
          out2 + ((size_t)((bb << 3) + headq) * HD + dbase + dl) * NN + nnb;
      *(uint4*)&vdst[cc] = r0;
      *(uint4*)&vdst[cc + 8] = r1;
    }
  } else {
    // residual half: outf = 0.5*(x@wr^T + br), fp32
#pragma unroll
    for (int j = 0; j < 4; ++j) {
      const int colb = n0 + wn + j * 16;
      const int o    = colb & 511;
      const float bi = 0.5f * __bfloat162float(bias1[o + fl]);
#pragma unroll
      for (int i = 0; i < 4; ++i) {
#pragma unroll
        for (int r = 0; r < 4; ++r) {
          const int row = m0 + wm + i * 16 + rb + r;
          outf[(size_t)row * OO + o + fl] = 0.5f * acc[i][j][r] + bi;
        }
      }
    }
  }
}

// ---------------------------------------------------------------------------
// Fused FFN (2 phases). 256 blocks x 1024 thr (16 waves), 32-row band per
// block. Each wave owns 32 output cols: acc[2][2], 4 MFMA/iter. Barrier-free
// K-loop; weights global->reg DEPTH-6 ring with end-of-iter sched_barrier(0)
// fence (r4/r7 lesson: unfenced rings collapse).
//   phase 1: h1 = relu(hb_band @ w1^T + b1) * rowmask -> h1s (in place)
//   phase 2: acc = h1 @ w2^T;  outf += 0.5*(acc + rowmask*b2)
// outf already holds 0.5*(x@wr^T+br) from gemm_qkv part 3.
// ---------------------------------------------------------------------------
__global__ __launch_bounds__(1024) void ffn_fused(
    const __hip_bfloat16* __restrict__ hb,
    const __hip_bfloat16* __restrict__ w1, const __hip_bfloat16* __restrict__ w2,
    const __hip_bfloat16* __restrict__ b1, const __hip_bfloat16* __restrict__ b2,
    const int* __restrict__ mask, float* __restrict__ outf) {
  __shared__ __align__(16) __hip_bfloat16 h1s[32 * 520];  // hb band, then h1
  __shared__ float Mrow[32];

  const int tid  = threadIdx.x;
  const int wv   = tid >> 6;       // 0..15, owns cols [wv*32, wv*32+32)
  const int lane = tid & 63;
  const int fl   = lane & 15;
  const int quad = lane >> 4;
  const int fk   = quad * 8;
  const int m0   = blockIdx.x * 32;

  // ---- pre-stage activation band into LDS (coalesced), row mask ----
  {
    const int col = (tid & 63) * 8;
#pragma unroll
    for (int c = 0; c < 2; ++c) {
      const int row = c * 16 + (tid >> 6);
      *(uint4*)&h1s[row * 520 + col] =
          *(const uint4*)&hb[(size_t)(m0 + row) * OO + col];
    }
    if (tid < 32) Mrow[tid] = (mask[m0 + tid] != 0) ? 1.f : 0.f;
  }
  __syncthreads();

  f32x4 acc[2][2];

  // One phase = 16 K-steps (K=32 each); depth-6 fenced register ring.
  auto run_phase = [&](const __hip_bfloat16* __restrict__ W) {
    const __hip_bfloat16* wl0 = W + (size_t)(wv * 32 + fl) * 512 + fk;
    short8 a[6][2];
#pragma unroll
    for (int d = 0; d < 6; ++d)
#pragma unroll
      for (int j = 0; j < 2; ++j)
        a[d][j] = *(const short8*)(wl0 + d * 32 + j * 8192);
#pragma unroll
    for (int k = 0; k < 16; ++k) {
      short8 bh_[2];
#pragma unroll
      for (int i = 0; i < 2; ++i)
        bh_[i] = *(const short8*)&h1s[(i * 16 + fl) * 520 + k * 32 + fk];
      __builtin_amdgcn_s_setprio(1);
#pragma unroll
      for (int j = 0; j < 2; ++j)
#pragma unroll
        for (int i = 0; i < 2; ++i)
          acc[i][j] = __builtin_amdgcn_mfma_f32_16x16x32_bf16(a[k % 6][j], bh_[i],
                                                              acc[i][j], 0, 0, 0);
      __builtin_amdgcn_s_setprio(0);
      if (k < 10) {
#pragma unroll
        for (int j = 0; j < 2; ++j)
          a[k % 6][j] = *(const short8*)(wl0 + (k + 6) * 32 + j * 8192);
      }
      __builtin_amdgcn_sched_barrier(0);  // pin ring reload in THIS iter
    }
  };

  // ---- phase 1: h1 = relu(hb @ w1^T + b1) * rowmask ----
#pragma unroll
  for (int i = 0; i < 2; ++i)
#pragma unroll
    for (int j = 0; j < 2; ++j) acc[i][j] = (f32x4){0.f, 0.f, 0.f, 0.f};
  run_phase(w1);
  __syncthreads();  // all waves done reading hb band from h1s

#pragma unroll
  for (int j = 0; j < 2; ++j) {
    const int c0 = wv * 32 + j * 16 + quad * 4;
    union { short4v s; __hip_bfloat16 h[4]; } bv;
    bv.s = *(const short4v*)&b1[c0];
#pragma unroll
    for (int i = 0; i < 2; ++i) {
      const float mr = Mrow[i * 16 + fl];
      union { short4v s; __hip_bfloat16 h[4]; } pu;
#pragma unroll
      for (int e = 0; e < 4; ++e) {
        const float v = fmaxf(acc[i][j][e] + __bfloat162float(bv.h[e]), 0.f) * mr;
        pu.h[e] = __float2bfloat16(v);
      }
      *(short4v*)&h1s[(i * 16 + fl) * 520 + c0] = pu.s;
    }
  }
  __syncthreads();  // h1 visible to all waves

  // ---- phase 2: acc = h1 @ w2^T; outf += 0.5*(acc + rowmask*b2) ----
#pragma unroll
  for (int i = 0; i < 2; ++i)
#pragma unroll
    for (int j = 0; j < 2; ++j) acc[i][j] = (f32x4){0.f, 0.f, 0.f, 0.f};
  run_phase(w2);

#pragma unroll
  for (int j = 0; j < 2; ++j) {
    const int c0 = wv * 32 + j * 16 + quad * 4;
    union { short4v s; __hip_bfloat16 h[4]; } b2v;
    b2v.s = *(const short4v*)&b2[c0];
#pragma unroll
    for (int i = 0; i < 2; ++i) {
      const float mr = Mrow[i * 16 + fl];
      const int row = m0 + i * 16 + fl;
      float4 prev = *(const float4*)&outf[(size_t)row * OO + c0];
      float4 o;
      o.x = prev.x + 0.5f * (acc[i][j][0] + mr * __bfloat162float(b2v.h[0]));
      o.y = prev.y + 0.5f * (acc[i][j][1] + mr * __bfloat162float(b2v.h[1]));
      o.z = prev.z + 0.5f * (acc[i][j][2] + mr * __bfloat162float(b2v.h[2]));
      o.w = prev.w + 0.5f * (acc[i][j][3] + mr * __bfloat162float(b2v.h[3]));
      *(float4*)&outf[(size_t)row * OO + c0] = o;
    }
  }
}

// ---------------------------------------------------------------------------
// Attention: 128-row Q tile, 256 threads (4 waves x 32 q-rows = 2 Q-frags
// per wave). Keeps r9's LDS amortization (kf/vf reads feed 2x MFMA) but
// restores TWO blocks/CU (grid 512, LDS 59.4KB -> 2 co-resident barrier
// domains; r9's 1 blk/CU left every barrier drain + softmax chain bubble
// uncovered -> MFMA 15%/VALU 47%, neither saturated). dbuf K/V single-
// barrier staging. S^T trick (A=K, B=Q); Ps aliased onto Qs; Q pre-scaled
// 0.125*log2(e); Msf fuses mask + shift (log2 domain). blockIdx = qblk*64+bh.
// ---------------------------------------------------------------------------
__global__ __launch_bounds__(256) void attn_kernel(
    const __hip_bfloat16* __restrict__ Qb, const __hip_bfloat16* __restrict__ Kb,
    const __hip_bfloat16* __restrict__ Vt, const __hip_bfloat16* __restrict__ slw,
    const int* __restrict__ mask, __hip_bfloat16* __restrict__ hb) {
  __shared__ __align__(16) __hip_bfloat16 QPs[128 * 72];  // Q pre-loop, then P
  __shared__ __align__(16) __hip_bfloat16 Ks[2][64 * 72];
  __shared__ __align__(16) __hip_bfloat16 Vs[2][64 * 72];
  __shared__ float Msf[NN];

  const int tid  = threadIdx.x;
  const int wave = tid >> 6;      // 0..3, owns q-rows [wave*32, wave*32+32)
  const int lane = tid & 63;
  const int fl   = lane & 15;
  const int quad = lane >> 4;
  const int fk   = quad * 8;
  const int rb   = quad * 4;
  const int bh   = blockIdx.x & 63;
  const int qblk = blockIdx.x >> 6;   // 0..7
  const int b    = bh >> 3;
  const int head = bh & 7;
  const int q0   = qblk * 128;

  const float slwL2 = __bfloat162float(slw[head]) * 1.44269504f;

  // diagonal self-loop tile/row indices per fragment (16-row granules)
  const int r16A = 8 * qblk + 2 * wave;      // frag A granule index
  const int r16B = r16A + 1;                 // frag B
  const int kbdA = r16A >> 2, jdA = r16A & 3;
  const int kbdB = r16B >> 2, jdB = r16B & 3;

  // staging geometry: K tile 64x64, V^T tile 64x64 -> 2 uint4/thread each
  const int srow2 = tid >> 2;        // 0..63
  const int sc2   = (tid & 3) * 16;  // 0,16,32,48
  const __hip_bfloat16* kgb = Kb + (size_t)bh * NN * HD;
  const __hip_bfloat16* vgb = Vt + (size_t)bh * HD * NN;

  // prologue: stage Q (128x64) + Msf; K/V tile0 -> buf0; prefetch tile1
  uint4 kr0 = *(const uint4*)(kgb + (size_t)srow2 * HD + sc2);
  uint4 kr1 = *(const uint4*)(kgb + (size_t)srow2 * HD + sc2 + 8);
  uint4 vr0 = *(const uint4*)(vgb + (size_t)srow2 * NN + sc2);
  uint4 vr1 = *(const uint4*)(vgb + (size_t)srow2 * NN + sc2 + 8);
  {
    const int qr = tid >> 1;           // 0..127
    const int qc = (tid & 1) * 32;     // 0 or 32
    const __hip_bfloat16* qg = Qb + ((size_t)bh * NN + q0 + qr) * HD + qc;
    uint4 v0 = *(const uint4*)(qg);
    uint4 v1 = *(const uint4*)(qg + 8);
    uint4 v2 = *(const uint4*)(qg + 16);
    uint4 v3 = *(const uint4*)(qg + 24);
    *(uint4*)&QPs[qr * 72 + qc] = v0;
    *(uint4*)&QPs[qr * 72 + qc + 8] = v1;
    *(uint4*)&QPs[qr * 72 + qc + 16] = v2;
    *(uint4*)&QPs[qr * 72 + qc + 24] = v3;
#pragma unroll
    for (int k = 0; k < 4; ++k) {
      const int idx = tid * 4 + k;
      Msf[idx] = (mask[b * NN + idx] != 0) ? KSHIFT : KMASKED;
    }
  }
  *(uint4*)&Ks[0][srow2 * 72 + sc2] = kr0;
  *(uint4*)&Ks[0][srow2 * 72 + sc2 + 8] = kr1;
  *(uint4*)&Vs[0][srow2 * 72 + sc2] = vr0;
  *(uint4*)&Vs[0][srow2 * 72 + sc2 + 8] = vr1;
  kr0 = *(const uint4*)(kgb + (size_t)(64 + srow2) * HD + sc2);
  kr1 = *(const uint4*)(kgb + (size_t)(64 + srow2) * HD + sc2 + 8);
  vr0 = *(const uint4*)(vgb + (size_t)srow2 * NN + 64 + sc2);
  vr1 = *(const uint4*)(vgb + (size_t)srow2 * NN + 64 + sc2 + 8);
  __syncthreads();
  // Q register-hoist (2 frags): QPs dead after this -> reused as P buffer.
  const short8 qa0A = *(const short8*)&QPs[(wave * 32 + fl) * 72 + fk];
  const short8 qa1A = *(const short8*)&QPs[(wave * 32 + fl) * 72 + fk + 32];
  const short8 qa0B = *(const short8*)&QPs[(wave * 32 + 16 + fl) * 72 + fk];
  const short8 qa1B = *(const short8*)&QPs[(wave * 32 + 16 + fl) * 72 + fk + 32];

  float lsumA = 0.f, lsumB = 0.f;
  f32x4 OaccA[4], OaccB[4];
#pragma unroll
  for (int t = 0; t < 4; ++t) {
    OaccA[t] = (f32x4){0.f, 0.f, 0.f, 0.f};
    OaccB[t] = (f32x4){0.f, 0.f, 0.f, 0.f};
  }

  for (int kb = 0; kb < NN / 64; ++kb) {
    const int kbase = kb * 64;
    const int cur   = kb & 1;
    const __hip_bfloat16* Kc = Ks[cur];
    const __hip_bfloat16* Vc = Vs[cur];

    f32x4 sfrA[4], sfrB[4];
    __builtin_amdgcn_s_setprio(1);
#pragma unroll
    for (int j = 0; j < 4; ++j) {
      const short8 kf0 = *(const short8*)&Kc[(j * 16 + fl) * 72 + fk];
      const short8 kf1 = *(const short8*)&Kc[(j * 16 + fl) * 72 + fk + 32];
      f32x4 zA = (f32x4){0.f, 0.f, 0.f, 0.f};
      zA = __builtin_amdgcn_mfma_f32_16x16x32_bf16(kf0, qa0A, zA, 0, 0, 0);
      zA = __builtin_amdgcn_mfma_f32_16x16x32_bf16(kf1, qa1A, zA, 0, 0, 0);
      sfrA[j] = zA;
      f32x4 zB = (f32x4){0.f, 0.f, 0.f, 0.f};
      zB = __builtin_amdgcn_mfma_f32_16x16x32_bf16(kf0, qa0B, zB, 0, 0, 0);
      zB = __builtin_amdgcn_mfma_f32_16x16x32_bf16(kf1, qa1B, zB, 0, 0, 0);
      sfrB[j] = zB;
    }
    __builtin_amdgcn_s_setprio(0);

    // diagonal self-loop bias (fully static element indexing)
    if ((fl >> 2) == quad && (kb == kbdA || kb == kbdB)) {
#pragma unroll
      for (int j = 0; j < 4; ++j)
#pragma unroll
        for (int e = 0; e < 4; ++e)
          if ((fl & 3) == e) {
            if (kb == kbdA && j == jdA) sfrA[j][e] += slwL2;
            if (kb == kbdB && j == jdB) sfrB[j][e] += slwL2;
          }
    }

#pragma unroll
    for (int j = 0; j < 4; ++j) {
      const f32x4 mb4 = *(const f32x4*)&Msf[kbase + j * 16 + quad * 4];
      union { short4v s; __hip_bfloat16 h[4]; } puA, puB;
      float psA = 0.f, psB = 0.f;
#pragma unroll
      for (int e = 0; e < 4; ++e) {
        const float pvA = exp2f(sfrA[j][e] + mb4[e]);
        psA += pvA;
        puA.h[e] = __float2bfloat16(pvA);
        const float pvB = exp2f(sfrB[j][e] + mb4[e]);
        psB += pvB;
        puB.h[e] = __float2bfloat16(pvB);
      }
      lsumA += psA;
      lsumB += psB;
      *(short4v*)&QPs[(wave * 32 + fl) * 72 + j * 16 + quad * 4] = puA.s;
      *(short4v*)&QPs[(wave * 32 + 16 + fl) * 72 + j * 16 + quad * 4] = puB.s;
    }

    const short8 paA0 = *(const short8*)&QPs[(wave * 32 + fl) * 72 + fk];
    const short8 paA1 = *(const short8*)&QPs[(wave * 32 + fl) * 72 + fk + 32];
    const short8 paB0 = *(const short8*)&QPs[(wave * 32 + 16 + fl) * 72 + fk];
    const short8 paB1 = *(const short8*)&QPs[(wave * 32 + 16 + fl) * 72 + fk + 32];
    __builtin_amdgcn_s_setprio(1);
#pragma unroll
    for (int t = 0; t < 4; ++t) {
      const short8 vf0 = *(const short8*)&Vc[(t * 16 + fl) * 72 + fk];
      const short8 vf1 = *(const short8*)&Vc[(t * 16 + fl) * 72 + fk + 32];
      OaccA[t] = __builtin_amdgcn_mfma_f32_16x16x32_bf16(paA0, vf0, OaccA[t], 0, 0, 0);
      OaccA[t] = __builtin_amdgcn_mfma_f32_16x16x32_bf16(paA1, vf1, OaccA[t], 0, 0, 0);
      OaccB[t] = __builtin_amdgcn_mfma_f32_16x16x32_bf16(paB0, vf0, OaccB[t], 0, 0, 0);
      OaccB[t] = __builtin_amdgcn_mfma_f32_16x16x32_bf16(paB1, vf1, OaccB[t], 0, 0, 0);
    }
    __builtin_amdgcn_s_setprio(0);

    // stage tile kb+1 into the other buffer (regs loaded last iter);
    // then issue tile kb+2 loads; fence; one barrier.
    if (kb + 1 < NN / 64) {
      *(uint4*)&Ks[cur ^ 1][srow2 * 72 + sc2] = kr0;
      *(uint4*)&Ks[cur ^ 1][srow2 * 72 + sc2 + 8] = kr1;
      *(uint4*)&Vs[cur ^ 1][srow2 * 72 + sc2] = vr0;
      *(uint4*)&Vs[cur ^ 1][srow2 * 72 + sc2 + 8] = vr1;
      if (kb + 2 < NN / 64) {
        const int nk = kbase + 128;
        kr0 = *(const uint4*)(kgb + (size_t)(nk + srow2) * HD + sc2);
        kr1 = *(const uint4*)(kgb + (size_t)(nk + srow2) * HD + sc2 + 8);
        vr0 = *(const uint4*)(vgb + (size_t)srow2 * NN + nk + sc2);
        vr1 = *(const uint4*)(vgb + (size_t)srow2 * NN + nk + sc2 + 8);
      }
      __builtin_amdgcn_sched_barrier(0);
      __syncthreads();
    }
  }

  // epilogue per fragment
#pragma unroll
  for (int f = 0; f < 2; ++f) {
    float l = (f == 0) ? lsumA : lsumB;
    l += __shfl_xor(l, 16, 64);
    l += __shfl_xor(l, 32, 64);
    const int qrow_me = q0 + wave * 32 + f * 16 + fl;
    const float qm = (mask[b * NN + qrow_me] != 0) ? 1.f : 0.f;
    const float sf = qm / fmaxf(l, 1e-30f);
    float scl[4];
#pragma unroll
    for (int r = 0; r < 4; ++r) scl[r] = __shfl(sf, rb + r, 64);
#pragma unroll
    for (int t = 0; t < 4; ++t) {
      const int d = t * 16 + fl;
#pragma unroll
      for (int r = 0; r < 4; ++r) {
        const int qrow_g = q0 + wave * 32 + f * 16 + rb + r;
        const float ov = (f == 0) ? OaccA[t][r] : OaccB[t][r];
        hb[(size_t)(b * NN + qrow_g) * OO + head * HD + d] =
            __float2bfloat16(ov * scl[r]);
      }
    }
  }
}

extern "C" void kernel_launch(void* const* d_in, const int* in_sizes, int n_in,
                              void* d_out, int out_size, void* d_ws, size_t ws_size,
                              hipStream_t stream) {
  const float* x_raw    = (const float*)d_in[0];
  const int* mask       = (const int*)d_in[2];
  const float* slw_raw  = (const float*)d_in[3];
  const float* qkvw_raw = (const float*)d_in[4];
  const float* qkvb_raw = (const float*)d_in[5];
  const float* w1_raw   = (const float*)d_in[6];
  const float* b1_raw   = (const float*)d_in[7];
  const float* w2_raw   = (const float*)d_in[8];
  const float* b2_raw   = (const float*)d_in[9];
  const float* wr_raw   = (const float*)d_in[10];
  const float* br_raw   = (const float*)d_in[11];
  float* outf           = (float*)d_out;

  __hip_bfloat16* p = (__hip_bfloat16*)d_ws;
  __hip_bfloat16* xc    = p; p += (size_t)MM * DD;
  __hip_bfloat16* qkvwc = p; p += 3 * OO * DD;   // contiguous with wrc:
  __hip_bfloat16* wrc   = p; p += OO * DD;       // B = [qkvw ; wr] 2048 rows
  __hip_bfloat16* w1c   = p; p += OO * OO;
  __hip_bfloat16* w2c   = p; p += OO * OO;
  __hip_bfloat16* qkvbc = p; p += 3 * OO;
  __hip_bfloat16* b1c   = p; p += OO;
  __hip_bfloat16* b2c   = p; p += OO;
  __hip_bfloat16* brc   = p; p += OO;
  __hip_bfloat16* slwc  = p; p += 64;
  const size_t ebuf = (size_t)BB * HH * NN * HD;
  __hip_bfloat16* Qb = p; p += ebuf;
  __hip_bfloat16* Kb = p; p += ebuf;
  __hip_bfloat16* Vb = p; p += ebuf;   // V^T layout [B,H,64,N]
  __hip_bfloat16* hb = p; p += ebuf;   // attn out (workspace; no d_out alias)

  if (ws_size < (size_t)((char*)p - (char*)d_ws)) return;

  ConvArgs ca;
  ca.src[0] = x_raw;    ca.dst[0] = xc;    ca.n4[0] = MM * DD / 4;
  ca.src[1] = qkvw_raw; ca.dst[1] = qkvwc; ca.n4[1] = 3 * OO * DD / 4;
  ca.src[2] = w1_raw;   ca.dst[2] = w1c;   ca.n4[2] = OO * OO / 4;
  ca.src[3] = w2_raw;   ca.dst[3] = w2c;   ca.n4[3] = OO * OO / 4;
  ca.src[4] = wr_raw;   ca.dst[4] = wrc;   ca.n4[4] = OO * DD / 4;
  ca.src[5] = qkvb_raw; ca.dst[5] = qkvbc; ca.n4[5] = 3 * OO / 4;
  ca.src[6] = b1_raw;   ca.dst[6] = b1c;   ca.n4[6] = OO / 4;
  ca.src[7] = b2_raw;   ca.dst[7] = b2c;   ca.n4[7] = OO / 4;
  ca.src[8] = br_raw;   ca.dst[8] = brc;   ca.n4[8] = OO / 4;
  ca.src[9] = slw_raw;  ca.dst[9] = slwc;  ca.n4[9] = HH / 4;
  convert_kernel<<<dim3(1024, SEG_N), 256, 0, stream>>>(ca);

  // 1) qkv + residual projection (XCD-banded, BK=64): Q/K/V + residual->outf
  gemm_qkv<<<1024, 256, 0, stream>>>(xc, qkvwc, qkvbc, brc, Qb, Kb, Vb, outf, DD);
  // 2) attention (+ query fmask) -> hb; 512 blocks x 256 thr (2 blk/CU)
  attn_kernel<<<BB * HH * (NN / 128), 256, 0, stream>>>(Qb, Kb, Vb, slwc, mask, hb);
  // 3) fused FFN (2 phases, 16-wave, fenced depth-6 ring) -> accumulate outf
  ffn_fused<<<256, 1024, 0, stream>>>(hb, w1c, w2c, b1c, b2c, mask, outf);
}

// Round 13
// 209.657 us; speedup vs baseline: 1.0019x; 1.0019x over previous
//
#include <hip/hip_runtime.h>
#include <hip/hip_bf16.h>

typedef __attribute__((ext_vector_type(8))) short short8;
typedef __attribute__((ext_vector_type(4))) float f32x4;
typedef __attribute__((ext_vector_type(4))) short short4v;

// Problem constants
#define BB 8
#define NN 1024
#define DD 512
#define OO 512
#define HH 8
#define HD 64
#define MM (BB * NN)  // 8192

#define QSC 0.18033688f       // 0.125 * log2(e): folded into Q at projection
#define KSHIFT -11.54156032f  // -8*log2(e): softmax shift, fused into key bias
#define KMASKED -30000.0f     // masked key: exp2 underflows to exactly 0

// Async global->LDS, 16B/lane (m97 recipe). LDS dest = wave-uniform base +
// lane*16 -> unpadded tiles.
__device__ __forceinline__ void gload_lds16(const void* g, void* l) {
  __builtin_amdgcn_global_load_lds(
      (const __attribute__((address_space(1))) void*)g,
      (__attribute__((address_space(3))) void*)l, 16, 0, 0);
}

__device__ __forceinline__ uint2 cvt4(float4 v) {
  union { uint2 u; __hip_bfloat16 h[4]; } t;
  t.h[0] = __float2bfloat16(v.x);
  t.h[1] = __float2bfloat16(v.y);
  t.h[2] = __float2bfloat16(v.z);
  t.h[3] = __float2bfloat16(v.w);
  return t.u;
}

// ---------------------------------------------------------------------------
// Input conversion. PROVEN: float inputs fp32, mask int32 {0,1}, output fp32.
// ---------------------------------------------------------------------------
#define SEG_N 10
struct ConvArgs {
  const float* src[SEG_N];
  __hip_bfloat16* dst[SEG_N];
  int n4[SEG_N];
};

__global__ void convert_kernel(ConvArgs a) {
  const int t = blockIdx.y;
  const int n4 = a.n4[t];
  const float4* fs = (const float4*)a.src[t];
  uint2* d = (uint2*)a.dst[t];
  for (int i = blockIdx.x * blockDim.x + threadIdx.x; i < n4;
       i += gridDim.x * blockDim.x)
    d[i] = cvt4(fs[i]);
}

// ---------------------------------------------------------------------------
// 128x128-tile GEMM, BK=64 via two-plane staging: smem = [A0|A1|B0|B1],
// each plane 128x32 (gload_lds linear-dest rule holds per plane). 8 barrier
// rounds, 8 gload_lds + 32 MFMA per round. B = [qkvw ; wr] (2048 rows).
// Grid 1024 = 64 rowparts x 16 colparts, XCD-banded.
// part 0: Q (pre-scaled QSC) -> [B,H,N,64]
// part 1: K                  -> [B,H,N,64]
// part 2: V (LDS transpose)  -> [B,H,64,N]
// part 3: 0.5*(x@wr^T + br)  -> fp32 d_out (residual half, pre-written;
//                               ffn_fused accumulates the h-half onto it)
// ---------------------------------------------------------------------------
__global__ __launch_bounds__(256) void gemm_qkv(
    const __hip_bfloat16* __restrict__ A0, const __hip_bfloat16* __restrict__ B0,
    const __hip_bfloat16* __restrict__ bias0, const __hip_bfloat16* __restrict__ bias1,
    __hip_bfloat16* __restrict__ out0, __hip_bfloat16* __restrict__ out1,
    __hip_bfloat16* __restrict__ out2, float* __restrict__ outf, int Kd) {
  __shared__ __align__(16) __hip_bfloat16 smem[16384];  // 4 planes x 128x32

  const int tid  = threadIdx.x;
  const int wave = tid >> 6;
  const int lane = tid & 63;
  const int fl   = lane & 15;
  const int fk   = (lane >> 4) * 8;
  const int wm   = (wave & 1) * 64;
  const int wn   = (wave >> 1) * 64;
  // XCD-banded swizzle (1024 blocks = 64 rowparts x 16 colparts)
  const int bid     = blockIdx.x;
  const int rowpart = 8 * (bid & 7) + ((bid >> 3) & 7);
  const int colpart = bid >> 6;
  const int m0 = rowpart * 128;
  const int n0 = colpart * 128;
  const int glr  = lane >> 2;
  const int glc  = (lane & 3) * 8;

  f32x4 acc[4][4];
#pragma unroll
  for (int i = 0; i < 4; ++i)
#pragma unroll
    for (int j = 0; j < 4; ++j) acc[i][j] = (f32x4){0.f, 0.f, 0.f, 0.f};

  char* lb = (char*)smem;
  for (int k0 = 0; k0 < Kd; k0 += 64) {
    __syncthreads();
    gload_lds16(A0 + (size_t)(m0 + wave * 16 + glr) * Kd + k0 + glc,
                lb + wave * 1024 + lane * 16);
    gload_lds16(A0 + (size_t)(m0 + 64 + wave * 16 + glr) * Kd + k0 + glc,
                lb + (wave + 4) * 1024 + lane * 16);
    gload_lds16(A0 + (size_t)(m0 + wave * 16 + glr) * Kd + k0 + 32 + glc,
                lb + 8192 + wave * 1024 + lane * 16);
    gload_lds16(A0 + (size_t)(m0 + 64 + wave * 16 + glr) * Kd + k0 + 32 + glc,
                lb + 8192 + (wave + 4) * 1024 + lane * 16);
    gload_lds16(B0 + (size_t)(n0 + wave * 16 + glr) * Kd + k0 + glc,
                lb + 16384 + wave * 1024 + lane * 16);
    gload_lds16(B0 + (size_t)(n0 + 64 + wave * 16 + glr) * Kd + k0 + glc,
                lb + 16384 + (wave + 4) * 1024 + lane * 16);
    gload_lds16(B0 + (size_t)(n0 + wave * 16 + glr) * Kd + k0 + 32 + glc,
                lb + 24576 + wave * 1024 + lane * 16);
    gload_lds16(B0 + (size_t)(n0 + 64 + wave * 16 + glr) * Kd + k0 + 32 + glc,
                lb + 24576 + (wave + 4) * 1024 + lane * 16);
    __syncthreads();

#pragma unroll
    for (int kh = 0; kh < 2; ++kh) {
      const __hip_bfloat16* Ap = smem + kh * 4096;
      const __hip_bfloat16* Bp = smem + 8192 + kh * 4096;
      short8 af[4], bfr[4];
#pragma unroll
      for (int i = 0; i < 4; ++i)
        af[i] = *(const short8*)&Ap[(wm + i * 16 + fl) * 32 + fk];
#pragma unroll
      for (int j = 0; j < 4; ++j)
        bfr[j] = *(const short8*)&Bp[(wn + j * 16 + fl) * 32 + fk];
#pragma unroll
      for (int i = 0; i < 4; ++i)
#pragma unroll
        for (int j = 0; j < 4; ++j)
          acc[i][j] = __builtin_amdgcn_mfma_f32_16x16x32_bf16(af[i], bfr[j],
                                                              acc[i][j], 0, 0, 0);
    }
  }

  const int rb = (lane >> 4) * 4;
  const int part = n0 >> 9;  // block-uniform: 0=Q 1=K 2=V 3=wr
  if (part < 2) {
    __hip_bfloat16* dst = (part == 0) ? out0 : out1;
    const float scf = (part == 0) ? QSC : 1.0f;
#pragma unroll
    for (int j = 0; j < 4; ++j) {
      const int colb  = n0 + wn + j * 16;
      const int o     = colb & 511;
      const int headq = o >> 6;
      const int d     = (o & 63) + fl;
      const float bi  = __bfloat162float(bias0[colb + fl]);
#pragma unroll
      for (int i = 0; i < 4; ++i) {
#pragma unroll
        for (int r = 0; r < 4; ++r) {
          const int row = m0 + wm + i * 16 + rb + r;
          const int bb  = row >> 10;
          const int nn  = row & 1023;
          dst[((size_t)((bb << 3) + headq) * NN + nn) * HD + d] =
              __float2bfloat16((acc[i][j][r] + bi) * scf);
        }
      }
    }
  } else if (part == 2) {
    // V: transpose 64x16 pieces through LDS, coalesced dwordx4 stores
    __syncthreads();  // uniform; smem free for scratch
    __hip_bfloat16* tsc = smem + wave * 1120;  // 16 x 70 per wave
    const int bb  = (m0 + wm) >> 10;
    const int nnb = (m0 + wm) & 1023;
    const int dl  = lane >> 2;
    const int cc  = (lane & 3) * 16;
#pragma unroll
    for (int j = 0; j < 4; ++j) {
      const int colb  = n0 + wn + j * 16;
      const int o     = colb & 511;
      const int headq = o >> 6;
      const int dbase = o & 63;
      const float bi  = __bfloat162float(bias0[colb + fl]);
#pragma unroll
      for (int i = 0; i < 4; ++i) {
#pragma unroll
        for (int r = 0; r < 4; ++r) {
          const int rr = i * 16 + rb + r;
          tsc[fl * 70 + rr] = __float2bfloat16(acc[i][j][r] + bi);
        }
      }
      uint4 r0 = *(const uint4*)&tsc[dl * 70 + cc];
      uint4 r1 = *(const uint4*)&tsc[dl * 70 + cc + 8];
      __hip_bfloat16* vdst =
          out2 + ((size_t)((bb << 3) + headq) * HD + dbase + dl) * NN + nnb;
      *(uint4*)&vdst[cc] = r0;
      *(uint4*)&vdst[cc + 8] = r1;
    }
  } else {
    // residual half: outf = 0.5*(x@wr^T + br), fp32
#pragma unroll
    for (int j = 0; j < 4; ++j) {
      const int colb = n0 + wn + j * 16;
      const int o    = colb & 511;
      const float bi = 0.5f * __bfloat162float(bias1[o + fl]);
#pragma unroll
      for (int i = 0; i < 4; ++i) {
#pragma unroll
        for (int r = 0; r < 4; ++r) {
          const int row = m0 + wm + i * 16 + rb + r;
          outf[(size_t)row * OO + o + fl] = 0.5f * acc[i][j][r] + bi;
        }
      }
    }
  }
}

// ---------------------------------------------------------------------------
// Fused FFN (2 phases). 256 blocks x 1024 thr (16 waves), 32-row band per
// block. Each wave owns 32 output cols: acc[2][2], 4 MFMA/iter. Barrier-free
// K-loop; weights global->reg DEPTH-6 ring with end-of-iter sched_barrier(0)
// fence (r4/r7 lesson: unfenced rings collapse).
//   phase 1: h1 = relu(hb_band @ w1^T + b1) * rowmask -> h1s (in place)
//   phase 2: acc = h1 @ w2^T;  outf += 0.5*(acc + rowmask*b2)
// outf already holds 0.5*(x@wr^T+br) from gemm_qkv part 3.
// ---------------------------------------------------------------------------
__global__ __launch_bounds__(1024) void ffn_fused(
    const __hip_bfloat16* __restrict__ hb,
    const __hip_bfloat16* __restrict__ w1, const __hip_bfloat16* __restrict__ w2,
    const __hip_bfloat16* __restrict__ b1, const __hip_bfloat16* __restrict__ b2,
    const int* __restrict__ mask, float* __restrict__ outf) {
  __shared__ __align__(16) __hip_bfloat16 h1s[32 * 520];  // hb band, then h1
  __shared__ float Mrow[32];

  const int tid  = threadIdx.x;
  const int wv   = tid >> 6;       // 0..15, owns cols [wv*32, wv*32+32)
  const int lane = tid & 63;
  const int fl   = lane & 15;
  const int quad = lane >> 4;
  const int fk   = quad * 8;
  const int m0   = blockIdx.x * 32;

  // ---- pre-stage activation band into LDS (coalesced), row mask ----
  {
    const int col = (tid & 63) * 8;
#pragma unroll
    for (int c = 0; c < 2; ++c) {
      const int row = c * 16 + (tid >> 6);
      *(uint4*)&h1s[row * 520 + col] =
          *(const uint4*)&hb[(size_t)(m0 + row) * OO + col];
    }
    if (tid < 32) Mrow[tid] = (mask[m0 + tid] != 0) ? 1.f : 0.f;
  }
  __syncthreads();

  f32x4 acc[2][2];

  // One phase = 16 K-steps (K=32 each); depth-6 fenced register ring.
  auto run_phase = [&](const __hip_bfloat16* __restrict__ W) {
    const __hip_bfloat16* wl0 = W + (size_t)(wv * 32 + fl) * 512 + fk;
    short8 a[6][2];
#pragma unroll
    for (int d = 0; d < 6; ++d)
#pragma unroll
      for (int j = 0; j < 2; ++j)
        a[d][j] = *(const short8*)(wl0 + d * 32 + j * 8192);
#pragma unroll
    for (int k = 0; k < 16; ++k) {
      short8 bh_[2];
#pragma unroll
      for (int i = 0; i < 2; ++i)
        bh_[i] = *(const short8*)&h1s[(i * 16 + fl) * 520 + k * 32 + fk];
      __builtin_amdgcn_s_setprio(1);
#pragma unroll
      for (int j = 0; j < 2; ++j)
#pragma unroll
        for (int i = 0; i < 2; ++i)
          acc[i][j] = __builtin_amdgcn_mfma_f32_16x16x32_bf16(a[k % 6][j], bh_[i],
                                                              acc[i][j], 0, 0, 0);
      __builtin_amdgcn_s_setprio(0);
      if (k < 10) {
#pragma unroll
        for (int j = 0; j < 2; ++j)
          a[k % 6][j] = *(const short8*)(wl0 + (k + 6) * 32 + j * 8192);
      }
      __builtin_amdgcn_sched_barrier(0);  // pin ring reload in THIS iter
    }
  };

  // ---- phase 1: h1 = relu(hb @ w1^T + b1) * rowmask ----
#pragma unroll
  for (int i = 0; i < 2; ++i)
#pragma unroll
    for (int j = 0; j < 2; ++j) acc[i][j] = (f32x4){0.f, 0.f, 0.f, 0.f};
  run_phase(w1);
  __syncthreads();  // all waves done reading hb band from h1s

#pragma unroll
  for (int j = 0; j < 2; ++j) {
    const int c0 = wv * 32 + j * 16 + quad * 4;
    union { short4v s; __hip_bfloat16 h[4]; } bv;
    bv.s = *(const short4v*)&b1[c0];
#pragma unroll
    for (int i = 0; i < 2; ++i) {
      const float mr = Mrow[i * 16 + fl];
      union { short4v s; __hip_bfloat16 h[4]; } pu;
#pragma unroll
      for (int e = 0; e < 4; ++e) {
        const float v = fmaxf(acc[i][j][e] + __bfloat162float(bv.h[e]), 0.f) * mr;
        pu.h[e] = __float2bfloat16(v);
      }
      *(short4v*)&h1s[(i * 16 + fl) * 520 + c0] = pu.s;
    }
  }
  __syncthreads();  // h1 visible to all waves

  // ---- phase 2: acc = h1 @ w2^T; outf += 0.5*(acc + rowmask*b2) ----
#pragma unroll
  for (int i = 0; i < 2; ++i)
#pragma unroll
    for (int j = 0; j < 2; ++j) acc[i][j] = (f32x4){0.f, 0.f, 0.f, 0.f};
  run_phase(w2);

#pragma unroll
  for (int j = 0; j < 2; ++j) {
    const int c0 = wv * 32 + j * 16 + quad * 4;
    union { short4v s; __hip_bfloat16 h[4]; } b2v;
    b2v.s = *(const short4v*)&b2[c0];
#pragma unroll
    for (int i = 0; i < 2; ++i) {
      const float mr = Mrow[i * 16 + fl];
      const int row = m0 + i * 16 + fl;
      float4 prev = *(const float4*)&outf[(size_t)row * OO + c0];
      float4 o;
      o.x = prev.x + 0.5f * (acc[i][j][0] + mr * __bfloat162float(b2v.h[0]));
      o.y = prev.y + 0.5f * (acc[i][j][1] + mr * __bfloat162float(b2v.h[1]));
      o.z = prev.z + 0.5f * (acc[i][j][2] + mr * __bfloat162float(b2v.h[2]));
      o.w = prev.w + 0.5f * (acc[i][j][3] + mr * __bfloat162float(b2v.h[3]));
      *(float4*)&outf[(size_t)row * OO + c0] = o;
    }
  }
}

// ---------------------------------------------------------------------------
// Attention, CROSS-TILE PIPELINE (r12 evidence: 3 orthogonal geometry
// variants all 42-43us, no pipe >52% -> binding constraint = per-tile serial
// chain QK->softmax->P-LDS-roundtrip->PV). New schedule per iteration:
//   stage(k+1) -> barrier -> QK(k+1) -> Pread(k)+PV(k) -> softmax(k+1)
// P round-trip hides under QK(k+1) MFMA; softmax hides under PV. P is
// single-buffered (wave-local; read-before-write is program-order-safe).
// K/V = 3-buffer ring: staging write of tile k+2 (buf (k+2)%3) is separated
// from PV(k)'s reads (buf k%3) by 2 barriers. LDS 77.8KB -> 2 blocks/CU.
// 256 thr (4 waves x 32 q-rows, 2 Q-frags). S^T trick; Q pre-scaled
// 0.125*log2(e); Msf fuses mask+shift (log2 domain). blockIdx = qblk*64+bh.
// ---------------------------------------------------------------------------
__global__ __launch_bounds__(256) void attn_kernel(
    const __hip_bfloat16* __restrict__ Qb, const __hip_bfloat16* __restrict__ Kb,
    const __hip_bfloat16* __restrict__ Vt, const __hip_bfloat16* __restrict__ slw,
    const int* __restrict__ mask, __hip_bfloat16* __restrict__ hb) {
  __shared__ __align__(16) __hip_bfloat16 QPs[128 * 72];   // Q pre-loop, then P
  __shared__ __align__(16) __hip_bfloat16 Ks[3][64 * 72];  // K ring
  __shared__ __align__(16) __hip_bfloat16 Vs[3][64 * 72];  // V ring
  __shared__ float Msf[NN];

  const int tid  = threadIdx.x;
  const int wave = tid >> 6;      // 0..3, owns q-rows [wave*32, wave*32+32)
  const int lane = tid & 63;
  const int fl   = lane & 15;
  const int quad = lane >> 4;
  const int fk   = quad * 8;
  const int rb   = quad * 4;
  const int bh   = blockIdx.x & 63;
  const int qblk = blockIdx.x >> 6;   // 0..7
  const int b    = bh >> 3;
  const int head = bh & 7;
  const int q0   = qblk * 128;

  const float slwL2 = __bfloat162float(slw[head]) * 1.44269504f;

  // diagonal self-loop tile/row indices per fragment (16-row granules)
  const int r16A = 8 * qblk + 2 * wave;
  const int r16B = r16A + 1;
  const int kbdA = r16A >> 2, jdA = r16A & 3;
  const int kbdB = r16B >> 2, jdB = r16B & 3;

  // staging geometry: K tile 64x64, V^T tile 64x64 -> 2 uint4/thread each
  const int srow2 = tid >> 2;        // 0..63
  const int sc2   = (tid & 3) * 16;  // 0,16,32,48
  const __hip_bfloat16* kgb = Kb + (size_t)bh * NN * HD;
  const __hip_bfloat16* vgb = Vt + (size_t)bh * HD * NN;

  // ---- prologue: stage Q + Msf; tile0 -> buf0; prefetch tile1 regs ----
  uint4 kr0 = *(const uint4*)(kgb + (size_t)srow2 * HD + sc2);
  uint4 kr1 = *(const uint4*)(kgb + (size_t)srow2 * HD + sc2 + 8);
  uint4 vr0 = *(const uint4*)(vgb + (size_t)srow2 * NN + sc2);
  uint4 vr1 = *(const uint4*)(vgb + (size_t)srow2 * NN + sc2 + 8);
  {
    const int qr = tid >> 1;           // 0..127
    const int qc = (tid & 1) * 32;     // 0 or 32
    const __hip_bfloat16* qg = Qb + ((size_t)bh * NN + q0 + qr) * HD + qc;
    uint4 v0 = *(const uint4*)(qg);
    uint4 v1 = *(const uint4*)(qg + 8);
    uint4 v2 = *(const uint4*)(qg + 16);
    uint4 v3 = *(const uint4*)(qg + 24);
    *(uint4*)&QPs[qr * 72 + qc] = v0;
    *(uint4*)&QPs[qr * 72 + qc + 8] = v1;
    *(uint4*)&QPs[qr * 72 + qc + 16] = v2;
    *(uint4*)&QPs[qr * 72 + qc + 24] = v3;
#pragma unroll
    for (int k = 0; k < 4; ++k) {
      const int idx = tid * 4 + k;
      Msf[idx] = (mask[b * NN + idx] != 0) ? KSHIFT : KMASKED;
    }
  }
  *(uint4*)&Ks[0][srow2 * 72 + sc2] = kr0;
  *(uint4*)&Ks[0][srow2 * 72 + sc2 + 8] = kr1;
  *(uint4*)&Vs[0][srow2 * 72 + sc2] = vr0;
  *(uint4*)&Vs[0][srow2 * 72 + sc2 + 8] = vr1;
  kr0 = *(const uint4*)(kgb + (size_t)(64 + srow2) * HD + sc2);
  kr1 = *(const uint4*)(kgb + (size_t)(64 + srow2) * HD + sc2 + 8);
  vr0 = *(const uint4*)(vgb + (size_t)srow2 * NN + 64 + sc2);
  vr1 = *(const uint4*)(vgb + (size_t)srow2 * NN + 64 + sc2 + 8);
  __syncthreads();
  // Q register-hoist (2 frags): QPs dead after this -> reused as P buffer.
  const short8 qa0A = *(const short8*)&QPs[(wave * 32 + fl) * 72 + fk];
  const short8 qa1A = *(const short8*)&QPs[(wave * 32 + fl) * 72 + fk + 32];
  const short8 qa0B = *(const short8*)&QPs[(wave * 32 + 16 + fl) * 72 + fk];
  const short8 qa1B = *(const short8*)&QPs[(wave * 32 + 16 + fl) * 72 + fk + 32];

  float lsumA = 0.f, lsumB = 0.f;
  f32x4 OaccA[4], OaccB[4];
#pragma unroll
  for (int t = 0; t < 4; ++t) {
    OaccA[t] = (f32x4){0.f, 0.f, 0.f, 0.f};
    OaccB[t] = (f32x4){0.f, 0.f, 0.f, 0.f};
  }

  f32x4 sfrA[4], sfrB[4];

  // QK of a tile from ring buffer Kc -> sfrA/sfrB
  auto qk_tile = [&](const __hip_bfloat16* Kc) {
    __builtin_amdgcn_s_setprio(1);
#pragma unroll
    for (int j = 0; j < 4; ++j) {
      const short8 kf0 = *(const short8*)&Kc[(j * 16 + fl) * 72 + fk];
      const short8 kf1 = *(const short8*)&Kc[(j * 16 + fl) * 72 + fk + 32];
      f32x4 zA = (f32x4){0.f, 0.f, 0.f, 0.f};
      zA = __builtin_amdgcn_mfma_f32_16x16x32_bf16(kf0, qa0A, zA, 0, 0, 0);
      zA = __builtin_amdgcn_mfma_f32_16x16x32_bf16(kf1, qa1A, zA, 0, 0, 0);
      sfrA[j] = zA;
      f32x4 zB = (f32x4){0.f, 0.f, 0.f, 0.f};
      zB = __builtin_amdgcn_mfma_f32_16x16x32_bf16(kf0, qa0B, zB, 0, 0, 0);
      zB = __builtin_amdgcn_mfma_f32_16x16x32_bf16(kf1, qa1B, zB, 0, 0, 0);
      sfrB[j] = zB;
    }
    __builtin_amdgcn_s_setprio(0);
  };

  // softmax of tile kb2 (diag bias + exp2 + P write + lsum)
  auto softmax_tile = [&](int kb2) {
    if ((fl >> 2) == quad && (kb2 == kbdA || kb2 == kbdB)) {
#pragma unroll
      for (int j = 0; j < 4; ++j)
#pragma unroll
        for (int e = 0; e < 4; ++e)
          if ((fl & 3) == e) {
            if (kb2 == kbdA && j == jdA) sfrA[j][e] += slwL2;
            if (kb2 == kbdB && j == jdB) sfrB[j][e] += slwL2;
          }
    }
    const int kbase = kb2 * 64;
#pragma unroll
    for (int j = 0; j < 4; ++j) {
      const f32x4 mb4 = *(const f32x4*)&Msf[kbase + j * 16 + quad * 4];
      union { short4v s; __hip_bfloat16 h[4]; } puA, puB;
      float psA = 0.f, psB = 0.f;
#pragma unroll
      for (int e = 0; e < 4; ++e) {
        const float pvA = exp2f(sfrA[j][e] + mb4[e]);
        psA += pvA;
        puA.h[e] = __float2bfloat16(pvA);
        const float pvB = exp2f(sfrB[j][e] + mb4[e]);
        psB += pvB;
        puB.h[e] = __float2bfloat16(pvB);
      }
      lsumA += psA;
      lsumB += psB;
      *(short4v*)&QPs[(wave * 32 + fl) * 72 + j * 16 + quad * 4] = puA.s;
      *(short4v*)&QPs[(wave * 32 + 16 + fl) * 72 + j * 16 + quad * 4] = puB.s;
    }
  };

  // PV of previously-softmaxed tile from ring buffer Vc
  auto pv_tile = [&](const __hip_bfloat16* Vc) {
    const short8 paA0 = *(const short8*)&QPs[(wave * 32 + fl) * 72 + fk];
    const short8 paA1 = *(const short8*)&QPs[(wave * 32 + fl) * 72 + fk + 32];
    const short8 paB0 = *(const short8*)&QPs[(wave * 32 + 16 + fl) * 72 + fk];
    const short8 paB1 = *(const short8*)&QPs[(wave * 32 + 16 + fl) * 72 + fk + 32];
    __builtin_amdgcn_s_setprio(1);
#pragma unroll
    for (int t = 0; t < 4; ++t) {
      const short8 vf0 = *(const short8*)&Vc[(t * 16 + fl) * 72 + fk];
      const short8 vf1 = *(const short8*)&Vc[(t * 16 + fl) * 72 + fk + 32];
      OaccA[t] = __builtin_amdgcn_mfma_f32_16x16x32_bf16(paA0, vf0, OaccA[t], 0, 0, 0);
      OaccA[t] = __builtin_amdgcn_mfma_f32_16x16x32_bf16(paA1, vf1, OaccA[t], 0, 0, 0);
      OaccB[t] = __builtin_amdgcn_mfma_f32_16x16x32_bf16(paB0, vf0, OaccB[t], 0, 0, 0);
      OaccB[t] = __builtin_amdgcn_mfma_f32_16x16x32_bf16(paB1, vf1, OaccB[t], 0, 0, 0);
    }
    __builtin_amdgcn_s_setprio(0);
  };

  // ---- pipeline prologue: QK(0) + softmax(0) ----
  qk_tile(Ks[0]);
  softmax_tile(0);

  // ---- main loop: iter kb handles stage(kb+1), QK(kb+1), PV(kb),
  //      softmax(kb+1). 15 iterations (kb = 0..14). ----
  for (int kb = 0; kb < NN / 64 - 1; ++kb) {
    const int nxt = kb + 1;
    const int nb  = nxt % 3;
    // stage tile nxt from prefetch regs (ring slot nb; last reader of this
    // slot was PV(nxt-3) two barriers ago)
    *(uint4*)&Ks[nb][srow2 * 72 + sc2] = kr0;
    *(uint4*)&Ks[nb][srow2 * 72 + sc2 + 8] = kr1;
    *(uint4*)&Vs[nb][srow2 * 72 + sc2] = vr0;
    *(uint4*)&Vs[nb][srow2 * 72 + sc2 + 8] = vr1;
    // prefetch tile kb+2 (full-iteration issue->use distance)
    if (kb + 2 < NN / 64) {
      const int nk = (kb + 2) * 64;
      kr0 = *(const uint4*)(kgb + (size_t)(nk + srow2) * HD + sc2);
      kr1 = *(const uint4*)(kgb + (size_t)(nk + srow2) * HD + sc2 + 8);
      vr0 = *(const uint4*)(vgb + (size_t)srow2 * NN + nk + sc2);
      vr1 = *(const uint4*)(vgb + (size_t)srow2 * NN + nk + sc2 + 8);
    }
    __builtin_amdgcn_sched_barrier(0);
    __syncthreads();  // tile nxt visible

    qk_tile(Ks[nb]);        // QK(nxt): MFMA covers PV's P-read latency
    pv_tile(Vs[kb % 3]);    // PV(kb): P(kb) written last iter (wave-local)
    softmax_tile(nxt);      // softmax(nxt) -> P write (after P read, same wave)
  }
  // epilogue: PV of last tile (15 % 3 == 0)
  pv_tile(Vs[(NN / 64 - 1) % 3]);

  // ---- normalize + store ----
#pragma unroll
  for (int f = 0; f < 2; ++f) {
    float l = (f == 0) ? lsumA : lsumB;
    l += __shfl_xor(l, 16, 64);
    l += __shfl_xor(l, 32, 64);
    const int qrow_me = q0 + wave * 32 + f * 16 + fl;
    const float qm = (mask[b * NN + qrow_me] != 0) ? 1.f : 0.f;
    const float sf = qm / fmaxf(l, 1e-30f);
    float scl[4];
#pragma unroll
    for (int r = 0; r < 4; ++r) scl[r] = __shfl(sf, rb + r, 64);
#pragma unroll
    for (int t = 0; t < 4; ++t) {
      const int d = t * 16 + fl;
#pragma unroll
      for (int r = 0; r < 4; ++r) {
        const int qrow_g = q0 + wave * 32 + f * 16 + rb + r;
        const float ov = (f == 0) ? OaccA[t][r] : OaccB[t][r];
        hb[(size_t)(b * NN + qrow_g) * OO + head * HD + d] =
            __float2bfloat16(ov * scl[r]);
      }
    }
  }
}

extern "C" void kernel_launch(void* const* d_in, const int* in_sizes, int n_in,
                              void* d_out, int out_size, void* d_ws, size_t ws_size,
                              hipStream_t stream) {
  const float* x_raw    = (const float*)d_in[0];
  const int* mask       = (const int*)d_in[2];
  const float* slw_raw  = (const float*)d_in[3];
  const float* qkvw_raw = (const float*)d_in[4];
  const float* qkvb_raw = (const float*)d_in[5];
  const float* w1_raw   = (const float*)d_in[6];
  const float* b1_raw   = (const float*)d_in[7];
  const float* w2_raw   = (const float*)d_in[8];
  const float* b2_raw   = (const float*)d_in[9];
  const float* wr_raw   = (const float*)d_in[10];
  const float* br_raw   = (const float*)d_in[11];
  float* outf           = (float*)d_out;

  __hip_bfloat16* p = (__hip_bfloat16*)d_ws;
  __hip_bfloat16* xc    = p; p += (size_t)MM * DD;
  __hip_bfloat16* qkvwc = p; p += 3 * OO * DD;   // contiguous with wrc:
  __hip_bfloat16* wrc   = p; p += OO * DD;       // B = [qkvw ; wr] 2048 rows
  __hip_bfloat16* w1c   = p; p += OO * OO;
  __hip_bfloat16* w2c   = p; p += OO * OO;
  __hip_bfloat16* qkvbc = p; p += 3 * OO;
  __hip_bfloat16* b1c   = p; p += OO;
  __hip_bfloat16* b2c   = p; p += OO;
  __hip_bfloat16* brc   = p; p += OO;
  __hip_bfloat16* slwc  = p; p += 64;
  const size_t ebuf = (size_t)BB * HH * NN * HD;
  __hip_bfloat16* Qb = p; p += ebuf;
  __hip_bfloat16* Kb = p; p += ebuf;
  __hip_bfloat16* Vb = p; p += ebuf;   // V^T layout [B,H,64,N]
  __hip_bfloat16* hb = p; p += ebuf;   // attn out (workspace; no d_out alias)

  if (ws_size < (size_t)((char*)p - (char*)d_ws)) return;

  ConvArgs ca;
  ca.src[0] = x_raw;    ca.dst[0] = xc;    ca.n4[0] = MM * DD / 4;
  ca.src[1] = qkvw_raw; ca.dst[1] = qkvwc; ca.n4[1] = 3 * OO * DD / 4;
  ca.src[2] = w1_raw;   ca.dst[2] = w1c;   ca.n4[2] = OO * OO / 4;
  ca.src[3] = w2_raw;   ca.dst[3] = w2c;   ca.n4[3] = OO * OO / 4;
  ca.src[4] = wr_raw;   ca.dst[4] = wrc;   ca.n4[4] = OO * DD / 4;
  ca.src[5] = qkvb_raw; ca.dst[5] = qkvbc; ca.n4[5] = 3 * OO / 4;
  ca.src[6] = b1_raw;   ca.dst[6] = b1c;   ca.n4[6] = OO / 4;
  ca.src[7] = b2_raw;   ca.dst[7] = b2c;   ca.n4[7] = OO / 4;
  ca.src[8] = br_raw;   ca.dst[8] = brc;   ca.n4[8] = OO / 4;
  ca.src[9] = slw_raw;  ca.dst[9] = slwc;  ca.n4[9] = HH / 4;
  convert_kernel<<<dim3(1024, SEG_N), 256, 0, stream>>>(ca);

  // 1) qkv + residual projection (XCD-banded, BK=64): Q/K/V + residual->outf
  gemm_qkv<<<1024, 256, 0, stream>>>(xc, qkvwc, qkvbc, brc, Qb, Kb, Vb, outf, DD);
  // 2) attention (+ query fmask) -> hb; 512 blocks x 256 thr, pipelined
  attn_kernel<<<BB * HH * (NN / 128), 256, 0, stream>>>(Qb, Kb, Vb, slwc, mask, hb);
  // 3) fused FFN (2 phases, 16-wave, fenced depth-6 ring) -> accumulate outf
  ffn_fused<<<256, 1024, 0, stream>>>(hb, w1c, w2c, b1c, b2c, mask, outf);
}

// Round 14
// 205.868 us; speedup vs baseline: 1.0204x; 1.0184x over previous
//
#include <hip/hip_runtime.h>
#include <hip/hip_bf16.h>

typedef __attribute__((ext_vector_type(8))) short short8;
typedef __attribute__((ext_vector_type(4))) float f32x4;
typedef __attribute__((ext_vector_type(4))) short short4v;

// Problem constants
#define BB 8
#define NN 1024
#define DD 512
#define OO 512
#define HH 8
#define HD 64
#define MM (BB * NN)  // 8192

#define QSC 0.18033688f       // 0.125 * log2(e): folded into Q at projection
#define KSHIFT -11.54156032f  // -8*log2(e): softmax shift, fused into key bias
#define KMASKED -30000.0f     // masked key: exp2 underflows to exactly 0

// Async global->LDS, 16B/lane (m97 recipe). LDS dest = wave-uniform base +
// lane*16 -> unpadded tiles.
__device__ __forceinline__ void gload_lds16(const void* g, void* l) {
  __builtin_amdgcn_global_load_lds(
      (const __attribute__((address_space(1))) void*)g,
      (__attribute__((address_space(3))) void*)l, 16, 0, 0);
}

__device__ __forceinline__ uint2 cvt4(float4 v) {
  union { uint2 u; __hip_bfloat16 h[4]; } t;
  t.h[0] = __float2bfloat16(v.x);
  t.h[1] = __float2bfloat16(v.y);
  t.h[2] = __float2bfloat16(v.z);
  t.h[3] = __float2bfloat16(v.w);
  return t.u;
}

// ---------------------------------------------------------------------------
// Input conversion. PROVEN: float inputs fp32, mask int32 {0,1}, output fp32.
// ---------------------------------------------------------------------------
#define SEG_N 10
struct ConvArgs {
  const float* src[SEG_N];
  __hip_bfloat16* dst[SEG_N];
  int n4[SEG_N];
};

__global__ void convert_kernel(ConvArgs a) {
  const int t = blockIdx.y;
  const int n4 = a.n4[t];
  const float4* fs = (const float4*)a.src[t];
  uint2* d = (uint2*)a.dst[t];
  for (int i = blockIdx.x * blockDim.x + threadIdx.x; i < n4;
       i += gridDim.x * blockDim.x)
    d[i] = cvt4(fs[i]);
}

// ---------------------------------------------------------------------------
// 128x128-tile GEMM, BK=64 via two-plane staging: smem = [A0|A1|B0|B1],
// each plane 128x32 (gload_lds linear-dest rule holds per plane). 8 barrier
// rounds, 8 gload_lds + 32 MFMA per round. B = [qkvw ; wr] (2048 rows).
// Grid 1024 = 64 rowparts x 16 colparts, XCD-banded.
// part 0: Q (pre-scaled QSC) -> [B,H,N,64]
// part 1: K                  -> [B,H,N,64]
// part 2: V (LDS transpose)  -> [B,H,64,N]
// part 3: 0.5*(x@wr^T + br)  -> fp32 d_out (residual half, pre-written;
//                               ffn_fused accumulates the h-half onto it)
// ---------------------------------------------------------------------------
__global__ __launch_bounds__(256) void gemm_qkv(
    const __hip_bfloat16* __restrict__ A0, const __hip_bfloat16* __restrict__ B0,
    const __hip_bfloat16* __restrict__ bias0, const __hip_bfloat16* __restrict__ bias1,
    __hip_bfloat16* __restrict__ out0, __hip_bfloat16* __restrict__ out1,
    __hip_bfloat16* __restrict__ out2, float* __restrict__ outf, int Kd) {
  __shared__ __align__(16) __hip_bfloat16 smem[16384];  // 4 planes x 128x32

  const int tid  = threadIdx.x;
  const int wave = tid >> 6;
  const int lane = tid & 63;
  const int fl   = lane & 15;
  const int fk   = (lane >> 4) * 8;
  const int wm   = (wave & 1) * 64;
  const int wn   = (wave >> 1) * 64;
  // XCD-banded swizzle (1024 blocks = 64 rowparts x 16 colparts)
  const int bid     = blockIdx.x;
  const int rowpart = 8 * (bid & 7) + ((bid >> 3) & 7);
  const int colpart = bid >> 6;
  const int m0 = rowpart * 128;
  const int n0 = colpart * 128;
  const int glr  = lane >> 2;
  const int glc  = (lane & 3) * 8;

  f32x4 acc[4][4];
#pragma unroll
  for (int i = 0; i < 4; ++i)
#pragma unroll
    for (int j = 0; j < 4; ++j) acc[i][j] = (f32x4){0.f, 0.f, 0.f, 0.f};

  char* lb = (char*)smem;
  for (int k0 = 0; k0 < Kd; k0 += 64) {
    __syncthreads();
    gload_lds16(A0 + (size_t)(m0 + wave * 16 + glr) * Kd + k0 + glc,
                lb + wave * 1024 + lane * 16);
    gload_lds16(A0 + (size_t)(m0 + 64 + wave * 16 + glr) * Kd + k0 + glc,
                lb + (wave + 4) * 1024 + lane * 16);
    gload_lds16(A0 + (size_t)(m0 + wave * 16 + glr) * Kd + k0 + 32 + glc,
                lb + 8192 + wave * 1024 + lane * 16);
    gload_lds16(A0 + (size_t)(m0 + 64 + wave * 16 + glr) * Kd + k0 + 32 + glc,
                lb + 8192 + (wave + 4) * 1024 + lane * 16);
    gload_lds16(B0 + (size_t)(n0 + wave * 16 + glr) * Kd + k0 + glc,
                lb + 16384 + wave * 1024 + lane * 16);
    gload_lds16(B0 + (size_t)(n0 + 64 + wave * 16 + glr) * Kd + k0 + glc,
                lb + 16384 + (wave + 4) * 1024 + lane * 16);
    gload_lds16(B0 + (size_t)(n0 + wave * 16 + glr) * Kd + k0 + 32 + glc,
                lb + 24576 + wave * 1024 + lane * 16);
    gload_lds16(B0 + (size_t)(n0 + 64 + wave * 16 + glr) * Kd + k0 + 32 + glc,
                lb + 24576 + (wave + 4) * 1024 + lane * 16);
    __syncthreads();

#pragma unroll
    for (int kh = 0; kh < 2; ++kh) {
      const __hip_bfloat16* Ap = smem + kh * 4096;
      const __hip_bfloat16* Bp = smem + 8192 + kh * 4096;
      short8 af[4], bfr[4];
#pragma unroll
      for (int i = 0; i < 4; ++i)
        af[i] = *(const short8*)&Ap[(wm + i * 16 + fl) * 32 + fk];
#pragma unroll
      for (int j = 0; j < 4; ++j)
        bfr[j] = *(const short8*)&Bp[(wn + j * 16 + fl) * 32 + fk];
#pragma unroll
      for (int i = 0; i < 4; ++i)
#pragma unroll
        for (int j = 0; j < 4; ++j)
          acc[i][j] = __builtin_amdgcn_mfma_f32_16x16x32_bf16(af[i], bfr[j],
                                                              acc[i][j], 0, 0, 0);
    }
  }

  const int rb = (lane >> 4) * 4;
  const int part = n0 >> 9;  // block-uniform: 0=Q 1=K 2=V 3=wr
  if (part < 2) {
    __hip_bfloat16* dst = (part == 0) ? out0 : out1;
    const float scf = (part == 0) ? QSC : 1.0f;
#pragma unroll
    for (int j = 0; j < 4; ++j) {
      const int colb  = n0 + wn + j * 16;
      const int o     = colb & 511;
      const int headq = o >> 6;
      const int d     = (o & 63) + fl;
      const float bi  = __bfloat162float(bias0[colb + fl]);
#pragma unroll
      for (int i = 0; i < 4; ++i) {
#pragma unroll
        for (int r = 0; r < 4; ++r) {
          const int row = m0 + wm + i * 16 + rb + r;
          const int bb  = row >> 10;
          const int nn  = row & 1023;
          dst[((size_t)((bb << 3) + headq) * NN + nn) * HD + d] =
              __float2bfloat16((acc[i][j][r] + bi) * scf);
        }
      }
    }
  } else if (part == 2) {
    // V: transpose 64x16 pieces through LDS, coalesced dwordx4 stores
    __syncthreads();  // uniform; smem free for scratch
    __hip_bfloat16* tsc = smem + wave * 1120;  // 16 x 70 per wave
    const int bb  = (m0 + wm) >> 10;
    const int nnb = (m0 + wm) & 1023;
    const int dl  = lane >> 2;
    const int cc  = (lane & 3) * 16;
#pragma unroll
    for (int j = 0; j < 4; ++j) {
      const int colb  = n0 + wn + j * 16;
      const int o     = colb & 511;
      const int headq = o >> 6;
      const int dbase = o & 63;
      const float bi  = __bfloat162float(bias0[colb + fl]);
#pragma unroll
      for (int i = 0; i < 4; ++i) {
#pragma unroll
        for (int r = 0; r < 4; ++r) {
          const int rr = i * 16 + rb + r;
          tsc[fl * 70 + rr] = __float2bfloat16(acc[i][j][r] + bi);
        }
      }
      uint4 r0 = *(const uint4*)&tsc[dl * 70 + cc];
      uint4 r1 = *(const uint4*)&tsc[dl * 70 + cc + 8];
      __hip_bfloat16* vdst =
          out2 + ((size_t)((bb << 3) + headq) * HD + dbase + dl) * NN + nnb;
      *(uint4*)&vdst[cc] = r0;
      *(uint4*)&vdst[cc + 8] = r1;
    }
  } else {
    // residual half: outf = 0.5*(x@wr^T + br), fp32
#pragma unroll
    for (int j = 0; j < 4; ++j) {
      const int colb = n0 + wn + j * 16;
      const int o    = colb & 511;
      const float bi = 0.5f * __bfloat162float(bias1[o + fl]);
#pragma unroll
      for (int i = 0; i < 4; ++i) {
#pragma unroll
        for (int r = 0; r < 4; ++r) {
          const int row = m0 + wm + i * 16 + rb + r;
          outf[(size_t)row * OO + o + fl] = 0.5f * acc[i][j][r] + bi;
        }
      }
    }
  }
}

// ---------------------------------------------------------------------------
// Fused FFN (2 phases). 256 blocks x 1024 thr (16 waves), 32-row band per
// block. Each wave owns 32 output cols: acc[2][2], 4 MFMA/iter. Barrier-free
// K-loop; weights global->reg DEPTH-6 ring with end-of-iter sched_barrier(0)
// fence (r4/r7 lesson: unfenced rings collapse).
//   phase 1: h1 = relu(hb_band @ w1^T + b1) * rowmask -> h1s (in place)
//   phase 2: acc = h1 @ w2^T;  outf += 0.5*(acc + rowmask*b2)
// outf already holds 0.5*(x@wr^T+br) from gemm_qkv part 3.
// ---------------------------------------------------------------------------
__global__ __launch_bounds__(1024) void ffn_fused(
    const __hip_bfloat16* __restrict__ hb,
    const __hip_bfloat16* __restrict__ w1, const __hip_bfloat16* __restrict__ w2,
    const __hip_bfloat16* __restrict__ b1, const __hip_bfloat16* __restrict__ b2,
    const int* __restrict__ mask, float* __restrict__ outf) {
  __shared__ __align__(16) __hip_bfloat16 h1s[32 * 520];  // hb band, then h1
  __shared__ float Mrow[32];

  const int tid  = threadIdx.x;
  const int wv   = tid >> 6;       // 0..15, owns cols [wv*32, wv*32+32)
  const int lane = tid & 63;
  const int fl   = lane & 15;
  const int quad = lane >> 4;
  const int fk   = quad * 8;
  const int m0   = blockIdx.x * 32;

  // ---- pre-stage activation band into LDS (coalesced), row mask ----
  {
    const int col = (tid & 63) * 8;
#pragma unroll
    for (int c = 0; c < 2; ++c) {
      const int row = c * 16 + (tid >> 6);
      *(uint4*)&h1s[row * 520 + col] =
          *(const uint4*)&hb[(size_t)(m0 + row) * OO + col];
    }
    if (tid < 32) Mrow[tid] = (mask[m0 + tid] != 0) ? 1.f : 0.f;
  }
  __syncthreads();

  f32x4 acc[2][2];

  // One phase = 16 K-steps (K=32 each); depth-6 fenced register ring.
  auto run_phase = [&](const __hip_bfloat16* __restrict__ W) {
    const __hip_bfloat16* wl0 = W + (size_t)(wv * 32 + fl) * 512 + fk;
    short8 a[6][2];
#pragma unroll
    for (int d = 0; d < 6; ++d)
#pragma unroll
      for (int j = 0; j < 2; ++j)
        a[d][j] = *(const short8*)(wl0 + d * 32 + j * 8192);
#pragma unroll
    for (int k = 0; k < 16; ++k) {
      short8 bh_[2];
#pragma unroll
      for (int i = 0; i < 2; ++i)
        bh_[i] = *(const short8*)&h1s[(i * 16 + fl) * 520 + k * 32 + fk];
      __builtin_amdgcn_s_setprio(1);
#pragma unroll
      for (int j = 0; j < 2; ++j)
#pragma unroll
        for (int i = 0; i < 2; ++i)
          acc[i][j] = __builtin_amdgcn_mfma_f32_16x16x32_bf16(a[k % 6][j], bh_[i],
                                                              acc[i][j], 0, 0, 0);
      __builtin_amdgcn_s_setprio(0);
      if (k < 10) {
#pragma unroll
        for (int j = 0; j < 2; ++j)
          a[k % 6][j] = *(const short8*)(wl0 + (k + 6) * 32 + j * 8192);
      }
      __builtin_amdgcn_sched_barrier(0);  // pin ring reload in THIS iter
    }
  };

  // ---- phase 1: h1 = relu(hb @ w1^T + b1) * rowmask ----
#pragma unroll
  for (int i = 0; i < 2; ++i)
#pragma unroll
    for (int j = 0; j < 2; ++j) acc[i][j] = (f32x4){0.f, 0.f, 0.f, 0.f};
  run_phase(w1);
  __syncthreads();  // all waves done reading hb band from h1s

#pragma unroll
  for (int j = 0; j < 2; ++j) {
    const int c0 = wv * 32 + j * 16 + quad * 4;
    union { short4v s; __hip_bfloat16 h[4]; } bv;
    bv.s = *(const short4v*)&b1[c0];
#pragma unroll
    for (int i = 0; i < 2; ++i) {
      const float mr = Mrow[i * 16 + fl];
      union { short4v s; __hip_bfloat16 h[4]; } pu;
#pragma unroll
      for (int e = 0; e < 4; ++e) {
        const float v = fmaxf(acc[i][j][e] + __bfloat162float(bv.h[e]), 0.f) * mr;
        pu.h[e] = __float2bfloat16(v);
      }
      *(short4v*)&h1s[(i * 16 + fl) * 520 + c0] = pu.s;
    }
  }
  __syncthreads();  // h1 visible to all waves

  // ---- phase 2: acc = h1 @ w2^T; outf += 0.5*(acc + rowmask*b2) ----
#pragma unroll
  for (int i = 0; i < 2; ++i)
#pragma unroll
    for (int j = 0; j < 2; ++j) acc[i][j] = (f32x4){0.f, 0.f, 0.f, 0.f};
  run_phase(w2);

#pragma unroll
  for (int j = 0; j < 2; ++j) {
    const int c0 = wv * 32 + j * 16 + quad * 4;
    union { short4v s; __hip_bfloat16 h[4]; } b2v;
    b2v.s = *(const short4v*)&b2[c0];
#pragma unroll
    for (int i = 0; i < 2; ++i) {
      const float mr = Mrow[i * 16 + fl];
      const int row = m0 + i * 16 + fl;
      float4 prev = *(const float4*)&outf[(size_t)row * OO + c0];
      float4 o;
      o.x = prev.x + 0.5f * (acc[i][j][0] + mr * __bfloat162float(b2v.h[0]));
      o.y = prev.y + 0.5f * (acc[i][j][1] + mr * __bfloat162float(b2v.h[1]));
      o.z = prev.z + 0.5f * (acc[i][j][2] + mr * __bfloat162float(b2v.h[2]));
      o.w = prev.w + 0.5f * (acc[i][j][3] + mr * __bfloat162float(b2v.h[3]));
      *(float4*)&outf[(size_t)row * OO + c0] = o;
    }
  }
}

// ---------------------------------------------------------------------------
// Attention: BEST-MEASURED geometry (r9/r10: QBLK=256, 512 thr, 8 waves x
// 32 q-rows = 2 Q-frags/wave; implied ~39us) + r13's cross-tile pipeline
// (verified -1.0us on the other geometry):
//   stage(k+1) -> barrier -> QK(k+1) -> Pread(k)+PV(k) -> softmax(k+1)
// P single-buffered (wave-local, read-before-write in program order).
// K/V 3-buffer ring (stage write of k+1 vs PV(k-2) reads: 2-barrier sep).
// LDS 96.3KB -> 1 blk/CU (as r9 was). S^T trick; Q pre-scaled 0.125*log2(e);
// Msf fuses mask+shift (log2 domain). blockIdx = qblk*64 + bh.
// ---------------------------------------------------------------------------
__global__ __launch_bounds__(512) void attn_kernel(
    const __hip_bfloat16* __restrict__ Qb, const __hip_bfloat16* __restrict__ Kb,
    const __hip_bfloat16* __restrict__ Vt, const __hip_bfloat16* __restrict__ slw,
    const int* __restrict__ mask, __hip_bfloat16* __restrict__ hb) {
  __shared__ __align__(16) __hip_bfloat16 QPs[256 * 72];   // Q pre-loop, then P
  __shared__ __align__(16) __hip_bfloat16 Ks[3][64 * 72];  // K ring
  __shared__ __align__(16) __hip_bfloat16 Vs[3][64 * 72];  // V ring
  __shared__ float Msf[NN];

  const int tid  = threadIdx.x;
  const int wave = tid >> 6;      // 0..7, owns q-rows [wave*32, wave*32+32)
  const int lane = tid & 63;
  const int fl   = lane & 15;
  const int quad = lane >> 4;
  const int fk   = quad * 8;
  const int rb   = quad * 4;
  const int bh   = blockIdx.x & 63;
  const int qblk = blockIdx.x >> 6;   // 0..3
  const int b    = bh >> 3;
  const int head = bh & 7;
  const int q0   = qblk * 256;

  const float slwL2 = __bfloat162float(slw[head]) * 1.44269504f;

  // diagonal self-loop tile/row indices per fragment (16-row granules)
  const int twf  = 2 * wave;
  const int kbdA = 4 * qblk + (twf >> 2);
  const int jdA  = twf & 3;
  const int kbdB = 4 * qblk + ((twf + 1) >> 2);
  const int jdB  = (twf + 1) & 3;

  // staging geometry: K tile 64x64, V^T tile 64x64 -> 1 uint4/thread each
  const int srow2 = tid >> 3;        // 0..63
  const int sc2   = (tid & 7) * 8;   // 0..56
  const __hip_bfloat16* kgb = Kb + (size_t)bh * NN * HD;
  const __hip_bfloat16* vgb = Vt + (size_t)bh * HD * NN;

  // ---- prologue: stage Q (256x64) + Msf; tile0 -> buf0; prefetch tile1 ----
  uint4 kr = *(const uint4*)(kgb + (size_t)srow2 * HD + sc2);
  uint4 vr = *(const uint4*)(vgb + (size_t)srow2 * NN + sc2);
  {
    const int qr = tid >> 1;           // 0..255
    const int qc = (tid & 1) * 32;     // 0 or 32
    const __hip_bfloat16* qg = Qb + ((size_t)bh * NN + q0 + qr) * HD + qc;
    uint4 v0 = *(const uint4*)(qg);
    uint4 v1 = *(const uint4*)(qg + 8);
    uint4 v2 = *(const uint4*)(qg + 16);
    uint4 v3 = *(const uint4*)(qg + 24);
    *(uint4*)&QPs[qr * 72 + qc] = v0;
    *(uint4*)&QPs[qr * 72 + qc + 8] = v1;
    *(uint4*)&QPs[qr * 72 + qc + 16] = v2;
    *(uint4*)&QPs[qr * 72 + qc + 24] = v3;
#pragma unroll
    for (int k = 0; k < 2; ++k) {
      const int idx = tid * 2 + k;
      Msf[idx] = (mask[b * NN + idx] != 0) ? KSHIFT : KMASKED;
    }
  }
  *(uint4*)&Ks[0][srow2 * 72 + sc2] = kr;
  *(uint4*)&Vs[0][srow2 * 72 + sc2] = vr;
  kr = *(const uint4*)(kgb + (size_t)(64 + srow2) * HD + sc2);
  vr = *(const uint4*)(vgb + (size_t)srow2 * NN + 64 + sc2);
  __syncthreads();
  // Q register-hoist (2 frags): QPs dead after this -> reused as P buffer.
  const short8 qa0A = *(const short8*)&QPs[(wave * 32 + fl) * 72 + fk];
  const short8 qa1A = *(const short8*)&QPs[(wave * 32 + fl) * 72 + fk + 32];
  const short8 qa0B = *(const short8*)&QPs[(wave * 32 + 16 + fl) * 72 + fk];
  const short8 qa1B = *(const short8*)&QPs[(wave * 32 + 16 + fl) * 72 + fk + 32];

  float lsumA = 0.f, lsumB = 0.f;
  f32x4 OaccA[4], OaccB[4];
#pragma unroll
  for (int t = 0; t < 4; ++t) {
    OaccA[t] = (f32x4){0.f, 0.f, 0.f, 0.f};
    OaccB[t] = (f32x4){0.f, 0.f, 0.f, 0.f};
  }

  f32x4 sfrA[4], sfrB[4];

  auto qk_tile = [&](const __hip_bfloat16* Kc) {
    __builtin_amdgcn_s_setprio(1);
#pragma unroll
    for (int j = 0; j < 4; ++j) {
      const short8 kf0 = *(const short8*)&Kc[(j * 16 + fl) * 72 + fk];
      const short8 kf1 = *(const short8*)&Kc[(j * 16 + fl) * 72 + fk + 32];
      f32x4 zA = (f32x4){0.f, 0.f, 0.f, 0.f};
      zA = __builtin_amdgcn_mfma_f32_16x16x32_bf16(kf0, qa0A, zA, 0, 0, 0);
      zA = __builtin_amdgcn_mfma_f32_16x16x32_bf16(kf1, qa1A, zA, 0, 0, 0);
      sfrA[j] = zA;
      f32x4 zB = (f32x4){0.f, 0.f, 0.f, 0.f};
      zB = __builtin_amdgcn_mfma_f32_16x16x32_bf16(kf0, qa0B, zB, 0, 0, 0);
      zB = __builtin_amdgcn_mfma_f32_16x16x32_bf16(kf1, qa1B, zB, 0, 0, 0);
      sfrB[j] = zB;
    }
    __builtin_amdgcn_s_setprio(0);
  };

  auto softmax_tile = [&](int kb2) {
    if ((fl >> 2) == quad && (kb2 == kbdA || kb2 == kbdB)) {
#pragma unroll
      for (int j = 0; j < 4; ++j)
#pragma unroll
        for (int e = 0; e < 4; ++e)
          if ((fl & 3) == e) {
            if (kb2 == kbdA && j == jdA) sfrA[j][e] += slwL2;
            if (kb2 == kbdB && j == jdB) sfrB[j][e] += slwL2;
          }
    }
    const int kbase = kb2 * 64;
#pragma unroll
    for (int j = 0; j < 4; ++j) {
      const f32x4 mb4 = *(const f32x4*)&Msf[kbase + j * 16 + quad * 4];
      union { short4v s; __hip_bfloat16 h[4]; } puA, puB;
      float psA = 0.f, psB = 0.f;
#pragma unroll
      for (int e = 0; e < 4; ++e) {
        const float pvA = exp2f(sfrA[j][e] + mb4[e]);
        psA += pvA;
        puA.h[e] = __float2bfloat16(pvA);
        const float pvB = exp2f(sfrB[j][e] + mb4[e]);
        psB += pvB;
        puB.h[e] = __float2bfloat16(pvB);
      }
      lsumA += psA;
      lsumB += psB;
      *(short4v*)&QPs[(wave * 32 + fl) * 72 + j * 16 + quad * 4] = puA.s;
      *(short4v*)&QPs[(wave * 32 + 16 + fl) * 72 + j * 16 + quad * 4] = puB.s;
    }
  };

  auto pv_tile = [&](const __hip_bfloat16* Vc) {
    const short8 paA0 = *(const short8*)&QPs[(wave * 32 + fl) * 72 + fk];
    const short8 paA1 = *(const short8*)&QPs[(wave * 32 + fl) * 72 + fk + 32];
    const short8 paB0 = *(const short8*)&QPs[(wave * 32 + 16 + fl) * 72 + fk];
    const short8 paB1 = *(const short8*)&QPs[(wave * 32 + 16 + fl) * 72 + fk + 32];
    __builtin_amdgcn_s_setprio(1);
#pragma unroll
    for (int t = 0; t < 4; ++t) {
      const short8 vf0 = *(const short8*)&Vc[(t * 16 + fl) * 72 + fk];
      const short8 vf1 = *(const short8*)&Vc[(t * 16 + fl) * 72 + fk + 32];
      OaccA[t] = __builtin_amdgcn_mfma_f32_16x16x32_bf16(paA0, vf0, OaccA[t], 0, 0, 0);
      OaccA[t] = __builtin_amdgcn_mfma_f32_16x16x32_bf16(paA1, vf1, OaccA[t], 0, 0, 0);
      OaccB[t] = __builtin_amdgcn_mfma_f32_16x16x32_bf16(paB0, vf0, OaccB[t], 0, 0, 0);
      OaccB[t] = __builtin_amdgcn_mfma_f32_16x16x32_bf16(paB1, vf1, OaccB[t], 0, 0, 0);
    }
    __builtin_amdgcn_s_setprio(0);
  };

  // ---- pipeline prologue: QK(0) + softmax(0) ----
  qk_tile(Ks[0]);
  softmax_tile(0);

  // ---- main loop: iter kb does stage(kb+1), QK(kb+1), PV(kb), softmax(kb+1)
  for (int kb = 0; kb < NN / 64 - 1; ++kb) {
    const int nxt = kb + 1;
    const int nb  = nxt % 3;
    *(uint4*)&Ks[nb][srow2 * 72 + sc2] = kr;
    *(uint4*)&Vs[nb][srow2 * 72 + sc2] = vr;
    if (kb + 2 < NN / 64) {
      const int nk = (kb + 2) * 64;
      kr = *(const uint4*)(kgb + (size_t)(nk + srow2) * HD + sc2);
      vr = *(const uint4*)(vgb + (size_t)srow2 * NN + nk + sc2);
    }
    __builtin_amdgcn_sched_barrier(0);
    __syncthreads();  // tile nxt visible

    qk_tile(Ks[nb]);        // QK(nxt): MFMA covers PV's P-read latency
    pv_tile(Vs[kb % 3]);    // PV(kb): P(kb) written last iter (wave-local)
    softmax_tile(nxt);      // softmax(nxt) -> P write (after P read)
  }
  pv_tile(Vs[(NN / 64 - 1) % 3]);  // epilogue: PV of last tile

  // ---- normalize + store ----
#pragma unroll
  for (int f = 0; f < 2; ++f) {
    float l = (f == 0) ? lsumA : lsumB;
    l += __shfl_xor(l, 16, 64);
    l += __shfl_xor(l, 32, 64);
    const int qrow_me = q0 + wave * 32 + f * 16 + fl;
    const float qm = (mask[b * NN + qrow_me] != 0) ? 1.f : 0.f;
    const float sf = qm / fmaxf(l, 1e-30f);
    float scl[4];
#pragma unroll
    for (int r = 0; r < 4; ++r) scl[r] = __shfl(sf, rb + r, 64);
#pragma unroll
    for (int t = 0; t < 4; ++t) {
      const int d = t * 16 + fl;
#pragma unroll
      for (int r = 0; r < 4; ++r) {
        const int qrow_g = q0 + wave * 32 + f * 16 + rb + r;
        const float ov = (f == 0) ? OaccA[t][r] : OaccB[t][r];
        hb[(size_t)(b * NN + qrow_g) * OO + head * HD + d] =
            __float2bfloat16(ov * scl[r]);
      }
    }
  }
}

extern "C" void kernel_launch(void* const* d_in, const int* in_sizes, int n_in,
                              void* d_out, int out_size, void* d_ws, size_t ws_size,
                              hipStream_t stream) {
  const float* x_raw    = (const float*)d_in[0];
  const int* mask       = (const int*)d_in[2];
  const float* slw_raw  = (const float*)d_in[3];
  const float* qkvw_raw = (const float*)d_in[4];
  const float* qkvb_raw = (const float*)d_in[5];
  const float* w1_raw   = (const float*)d_in[6];
  const float* b1_raw   = (const float*)d_in[7];
  const float* w2_raw   = (const float*)d_in[8];
  const float* b2_raw   = (const float*)d_in[9];
  const float* wr_raw   = (const float*)d_in[10];
  const float* br_raw   = (const float*)d_in[11];
  float* outf           = (float*)d_out;

  __hip_bfloat16* p = (__hip_bfloat16*)d_ws;
  __hip_bfloat16* xc    = p; p += (size_t)MM * DD;
  __hip_bfloat16* qkvwc = p; p += 3 * OO * DD;   // contiguous with wrc:
  __hip_bfloat16* wrc   = p; p += OO * DD;       // B = [qkvw ; wr] 2048 rows
  __hip_bfloat16* w1c   = p; p += OO * OO;
  __hip_bfloat16* w2c   = p; p += OO * OO;
  __hip_bfloat16* qkvbc = p; p += 3 * OO;
  __hip_bfloat16* b1c   = p; p += OO;
  __hip_bfloat16* b2c   = p; p += OO;
  __hip_bfloat16* brc   = p; p += OO;
  __hip_bfloat16* slwc  = p; p += 64;
  const size_t ebuf = (size_t)BB * HH * NN * HD;
  __hip_bfloat16* Qb = p; p += ebuf;
  __hip_bfloat16* Kb = p; p += ebuf;
  __hip_bfloat16* Vb = p; p += ebuf;   // V^T layout [B,H,64,N]
  __hip_bfloat16* hb = p; p += ebuf;   // attn out (workspace; no d_out alias)

  if (ws_size < (size_t)((char*)p - (char*)d_ws)) return;

  ConvArgs ca;
  ca.src[0] = x_raw;    ca.dst[0] = xc;    ca.n4[0] = MM * DD / 4;
  ca.src[1] = qkvw_raw; ca.dst[1] = qkvwc; ca.n4[1] = 3 * OO * DD / 4;
  ca.src[2] = w1_raw;   ca.dst[2] = w1c;   ca.n4[2] = OO * OO / 4;
  ca.src[3] = w2_raw;   ca.dst[3] = w2c;   ca.n4[3] = OO * OO / 4;
  ca.src[4] = wr_raw;   ca.dst[4] = wrc;   ca.n4[4] = OO * DD / 4;
  ca.src[5] = qkvb_raw; ca.dst[5] = qkvbc; ca.n4[5] = 3 * OO / 4;
  ca.src[6] = b1_raw;   ca.dst[6] = b1c;   ca.n4[6] = OO / 4;
  ca.src[7] = b2_raw;   ca.dst[7] = b2c;   ca.n4[7] = OO / 4;
  ca.src[8] = br_raw;   ca.dst[8] = brc;   ca.n4[8] = OO / 4;
  ca.src[9] = slw_raw;  ca.dst[9] = slwc;  ca.n4[9] = HH / 4;
  convert_kernel<<<dim3(1024, SEG_N), 256, 0, stream>>>(ca);

  // 1) qkv + residual projection (XCD-banded, BK=64): Q/K/V + residual->outf
  gemm_qkv<<<1024, 256, 0, stream>>>(xc, qkvwc, qkvbc, brc, Qb, Kb, Vb, outf, DD);
  // 2) attention (+ query fmask) -> hb; 256 blocks x 512 thr, pipelined
  attn_kernel<<<BB * HH * (NN / 256), 512, 0, stream>>>(Qb, Kb, Vb, slwc, mask, hb);
  // 3) fused FFN (2 phases, 16-wave, fenced depth-6 ring) -> accumulate outf
  ffn_fused<<<256, 1024, 0, stream>>>(hb, w1c, w2c, b1c, b2c, mask, outf);
}